// Round 16
// baseline (238.314 us; speedup 1.0000x reference)
//
#include <hip/hip_runtime.h>
#include <math.h>

#define NQ 2048
#define MKV 2048
#define BZ 2
#define DM 1024
#define NH 16
#define DH 64
#define RTAB 4095  /* NQ + MKV - 1 */
#define R0TAB 1984 /* lowest table row reachable under causal mask; == 0 mod 8 */
#define MTAB (RTAB - R0TAB) /* 2111 */
#define LOG2E 1.44269504088896340736f

typedef __bf16 bf16x8 __attribute__((ext_vector_type(8)));
typedef float f32x4 __attribute__((ext_vector_type(4)));

// native f32->bf16 (single v_cvt; lo plane captures the residual of whatever hi rounds to)
__device__ inline unsigned short f2bf(float x) {
  __bf16 b = (__bf16)x;
  union { __bf16 b; unsigned short u; } v; v.b = b; return v.u;
}
__device__ inline float bf2f(unsigned short h) {
  union { unsigned u; float f; } v; v.u = ((unsigned)h) << 16; return v.f;
}
// raw v_exp_f32 (D = 2^S0)
__device__ inline float fexp2(float x) { return __builtin_amdgcn_exp2f(x); }

// exact mod-192 for 0 <= G < 2^16:  floor(G/192) = floor((G>>6)/3), 43691=(2^17+1)/3
__device__ inline int slot192(int G) {
  int q3 = ((G >> 6) * 43691) >> 17;
  return G - 192 * q3;
}

// DPP row_ror:N within 16-lane rows (VALU pipe, not LDS)
template <int N>
__device__ inline float ror16(float x) {
  union { float f; int i; } a, r;
  a.f = x;
  r.i = __builtin_amdgcn_mov_dpp(a.i, 0x120 | N, 0xf, 0xf, true);
  return r.f;
}
__device__ inline float rowmax16(float x) {
  x = fmaxf(x, ror16<1>(x));
  x = fmaxf(x, ror16<2>(x));
  x = fmaxf(x, ror16<4>(x));
  x = fmaxf(x, ror16<8>(x));
  return x;
}
__device__ inline float rowsum16(float x) {
  x += ror16<1>(x);
  x += ror16<2>(x);
  x += ror16<4>(x);
  x += ror16<8>(x);
  return x;
}

#define SWZ(r, b) ((b) ^ (((r) & 7) << 4))
// V^T layout, conflict-free on BOTH b16 scatter-write and b128 read
#define VSWZ(dv, m) \
  ((dv) * 128 + (((((m) >> 3) ^ ((dv) & 7) ^ (((dv) >> 3) & 7)) << 4)) + ((m) & 7) * 2)

__device__ inline void gload_lds16(const void* g, void* l) {
  __builtin_amdgcn_global_load_lds((const __attribute__((address_space(1))) void*)g,
                                   (__attribute__((address_space(3))) void*)l, 16, 0, 0);
}

// ---------------- fused prep: fp32->(hi,lo) split for 6 inputs + sincos table ----------------
__global__ __launch_bounds__(256) void prep_kernel(
    const float* __restrict__ i0, unsigned short* __restrict__ h0, unsigned short* __restrict__ l0, int n0,
    const float* __restrict__ i1, unsigned short* __restrict__ h1, unsigned short* __restrict__ l1, int n1,
    const float* __restrict__ i2, unsigned short* __restrict__ h2, unsigned short* __restrict__ l2, int n2,
    const float* __restrict__ i3, unsigned short* __restrict__ h3, unsigned short* __restrict__ l3, int n3,
    const float* __restrict__ i4, unsigned short* __restrict__ h4, unsigned short* __restrict__ l4, int n4_,
    const float* __restrict__ i5, unsigned short* __restrict__ h5, unsigned short* __restrict__ l5, int n5,
    unsigned short* __restrict__ schi, unsigned short* __restrict__ sclo) {
  if (blockIdx.y == 6) {
    for (int idx = blockIdx.x * 256 + threadIdx.x; idx < MTAB * DM; idx += gridDim.x * 256) {
      int r = idx / DM;
      int b = idx - r * DM;
      int i = (b < DM / 2) ? b : (b - DM / 2);
      double fr = exp((double)i * (-9.210340371976184 / 512.0));
      float rr = (float)(R0TAB + r - (MKV - 1));
      float ph = rr * (float)fr;
      float val = (b < DM / 2) ? sinf(ph) : cosf(ph);
      unsigned short hb = f2bf(val);
      schi[idx] = hb;
      sclo[idx] = f2bf(val - bf2f(hb));
    }
    return;
  }
  const float* in; unsigned short* hp; unsigned short* lp; int n4;
  switch (blockIdx.y) {
    case 0: in = i0; hp = h0; lp = l0; n4 = n0; break;
    case 1: in = i1; hp = h1; lp = l1; n4 = n1; break;
    case 2: in = i2; hp = h2; lp = l2; n4 = n2; break;
    case 3: in = i3; hp = h3; lp = l3; n4 = n3; break;
    case 4: in = i4; hp = h4; lp = l4; n4 = n4_; break;
    default: in = i5; hp = h5; lp = l5; n4 = n5; break;
  }
  for (int i = blockIdx.x * 256 + threadIdx.x; i < n4; i += gridDim.x * 256) {
    float4 v = ((const float4*)in)[i];
    float f[4] = {v.x, v.y, v.z, v.w};
    ushort4 hq, lq;
    unsigned short* hh = (unsigned short*)&hq;
    unsigned short* ll = (unsigned short*)&lq;
#pragma unroll
    for (int e = 0; e < 4; ++e) {
      unsigned short hb = f2bf(f[e]);
      hh[e] = hb;
      ll[e] = f2bf(f[e] - bf2f(hb));
    }
    ((ushort4*)hp)[i] = hq;
    ((ushort4*)lp)[i] = lq;
  }
}

// ---------------- split-bf16 MFMA NT GEMM body (K = 1024 fixed) ----------------
template <int SPLIT_OUT, int KVSKIP>
__device__ __forceinline__ void gemm_body(
    const unsigned short* __restrict__ Ahi, const unsigned short* __restrict__ Alo,
    const unsigned short* __restrict__ Bhi, const unsigned short* __restrict__ Blo,
    float* __restrict__ Cf, unsigned short* __restrict__ Chi, unsigned short* __restrict__ Clo,
    int M, int N, int row0, int col0, char* lds, float cscale) {
  const int K = 1024;
  char* sAh = lds;
  char* sAl = lds + 16384;
  char* sBh = lds + 32768;
  char* sBl = lds + 49152;
  const int t = threadIdx.x;
  const int w = t >> 6;
  const int lane = t & 63;
  const int lo = lane & 15;
  const int hi = lane >> 4;
  const int wm = w >> 1, wn = w & 1;

  f32x4 acc[4][4];
#pragma unroll
  for (int a = 0; a < 4; ++a)
#pragma unroll
    for (int b = 0; b < 4; ++b) acc[a][b] = (f32x4){0.f, 0.f, 0.f, 0.f};

  for (int k0 = 0; k0 < K; k0 += 64) {
#pragma unroll
    for (int i = 0; i < 4; ++i) {
      int L = i * 4096 + t * 16;
      int r = L >> 7;
      int c16 = (L >> 4) & 7;
      int g16 = c16 ^ (r & 7);
      int ra = row0 + r;
      if (ra >= M) ra = M - 1;
      int rb = col0 + r;
      const char* gah = (const char*)(Ahi + (size_t)ra * K + k0) + g16 * 16;
      const char* gal = (const char*)(Alo + (size_t)ra * K + k0) + g16 * 16;
      const char* gbh = (const char*)(Bhi + (size_t)rb * K + k0) + g16 * 16;
      const char* gbl = (const char*)(Blo + (size_t)rb * K + k0) + g16 * 16;
      gload_lds16(gah, sAh + L);
      gload_lds16(gal, sAl + L);
      gload_lds16(gbh, sBh + L);
      gload_lds16(gbl, sBl + L);
    }
    __syncthreads();
#pragma unroll
    for (int ks = 0; ks < 2; ++ks) {
      bf16x8 ah[4], al[4], bh[4], bl[4];
#pragma unroll
      for (int f = 0; f < 4; ++f) {
        int rA = wm * 64 + 16 * f + lo;
        int offA = rA * 128 + (((4 * ks + hi) ^ (rA & 7)) << 4);
        ah[f] = *(const bf16x8*)(sAh + offA);
        al[f] = *(const bf16x8*)(sAl + offA);
        int rB = wn * 64 + 16 * f + lo;
        int offB = rB * 128 + (((4 * ks + hi) ^ (rB & 7)) << 4);
        bh[f] = *(const bf16x8*)(sBh + offB);
        bl[f] = *(const bf16x8*)(sBl + offB);
      }
#pragma unroll
      for (int fm = 0; fm < 4; ++fm)
#pragma unroll
        for (int fn = 0; fn < 4; ++fn) {
          acc[fm][fn] = __builtin_amdgcn_mfma_f32_16x16x32_bf16(ah[fm], bh[fn], acc[fm][fn], 0, 0, 0);
          acc[fm][fn] = __builtin_amdgcn_mfma_f32_16x16x32_bf16(ah[fm], bl[fn], acc[fm][fn], 0, 0, 0);
          acc[fm][fn] = __builtin_amdgcn_mfma_f32_16x16x32_bf16(al[fm], bh[fn], acc[fm][fn], 0, 0, 0);
        }
    }
    __syncthreads();
  }
  // epilogue
#pragma unroll
  for (int fm = 0; fm < 4; ++fm)
#pragma unroll
    for (int qq = 0; qq < 4; ++qq) {
      int row = row0 + wm * 64 + 16 * fm + 4 * hi + qq;
      if (row < M) {
#pragma unroll
        for (int fn = 0; fn < 4; ++fn) {
          int col = col0 + wn * 64 + 16 * fn + lo;
          float v = acc[fm][fn][qq] * cscale;
          if (SPLIT_OUT) {
            unsigned short hb = f2bf(v);
            Chi[(size_t)row * N + col] = hb;
            if (!KVSKIP || wn == 0)
              Clo[(size_t)row * N + col] = f2bf(v - bf2f(hb));
          } else {
            Cf[(size_t)row * N + col] = v;
          }
        }
      }
    }
}

// ---------------- fused 3-GEMM dispatch: q(256 blk) + kv(512 blk) + tab(136 blk) ----------------
__global__ __launch_bounds__(256, 2) void gemm3_kernel(
    const unsigned short* __restrict__ xqh, const unsigned short* __restrict__ xql,
    const unsigned short* __restrict__ tqh, const unsigned short* __restrict__ tql,
    unsigned short* __restrict__ qh, unsigned short* __restrict__ ql,
    const unsigned short* __restrict__ xkh, const unsigned short* __restrict__ xkl,
    const unsigned short* __restrict__ tkh, const unsigned short* __restrict__ tkl,
    unsigned short* __restrict__ kvh, unsigned short* __restrict__ kvl,
    const unsigned short* __restrict__ sch, const unsigned short* __restrict__ scl,
    const unsigned short* __restrict__ fph, const unsigned short* __restrict__ fpl,
    unsigned short* __restrict__ tbh, unsigned short* __restrict__ tbl) {
  __shared__ char lds[65536];
  int bx = blockIdx.x;
  if (bx < 256) {        // q = x_q @ to_q^T : scaled by log2e (q feeds only logits)
    int gx = bx & 7, gy = bx >> 3;
    gemm_body<1, 0>(xqh, xql, tqh, tql, nullptr, qh, ql, 4096, 1024, gy * 128, gx * 128, lds, LOG2E);
  } else if (bx < 768) { // kv = x_kv @ to_kv^T (V-half lo stores skipped)
    bx -= 256;
    int gx = bx & 15, gy = bx >> 4;
    gemm_body<1, 1>(xkh, xkl, tkh, tkl, nullptr, kvh, kvl, 4096, 2048, gy * 128, gx * 128, lds, 1.0f);
  } else {               // tab = sincos @ fpe^T
    bx -= 768;
    int gx = bx & 7, gy = bx >> 3;
    gemm_body<1, 0>(sch, scl, fph, fpl, nullptr, tbh, tbl, MTAB, 1024, gy * 128, gx * 128, lds, 1.0f);
  }
}

// ---------------- out GEMM: plain bf16, 64x128 tile (512 blocks) ----------------
__global__ __launch_bounds__(256, 2) void gemm_out_kernel(
    const unsigned short* __restrict__ A,   // at_hi [4096][1024]
    const unsigned short* __restrict__ B,   // to_hi [1024][1024]
    float* __restrict__ C) {
  __shared__ __align__(16) char sA[8192];
  __shared__ __align__(16) char sB[16384];
  const int t = threadIdx.x;
  const int w = t >> 6;
  const int lane = t & 63;
  const int lo = lane & 15;
  const int hi = lane >> 4;
  const int row0 = blockIdx.y * 64;
  const int col0 = blockIdx.x * 128;

  f32x4 acc[4][2];
#pragma unroll
  for (int a = 0; a < 4; ++a)
#pragma unroll
    for (int b = 0; b < 2; ++b) acc[a][b] = (f32x4){0.f, 0.f, 0.f, 0.f};

  for (int k0 = 0; k0 < 1024; k0 += 64) {
#pragma unroll
    for (int it = 0; it < 2; ++it) {
      int f = it * 256 + t;
      int r = f >> 3;
      int c = f & 7;
      int g16 = c ^ (r & 7);
      gload_lds16(A + (size_t)(row0 + r) * 1024 + k0 + g16 * 8, sA + f * 16);
    }
#pragma unroll
    for (int it = 0; it < 4; ++it) {
      int f = it * 256 + t;
      int r = f >> 3;
      int c = f & 7;
      int g16 = c ^ (r & 7);
      gload_lds16(B + (size_t)(col0 + r) * 1024 + k0 + g16 * 8, sB + f * 16);
    }
    __syncthreads();
#pragma unroll
    for (int ks = 0; ks < 2; ++ks) {
      bf16x8 af[4], bf_[2];
#pragma unroll
      for (int f = 0; f < 4; ++f) {
        int rA = 16 * f + lo;
        af[f] = *(const bf16x8*)(sA + rA * 128 + (((4 * ks + hi) ^ (rA & 7)) << 4));
      }
#pragma unroll
      for (int f = 0; f < 2; ++f) {
        int rB = 32 * w + 16 * f + lo;
        bf_[f] = *(const bf16x8*)(sB + rB * 128 + (((4 * ks + hi) ^ (rB & 7)) << 4));
      }
#pragma unroll
      for (int fm = 0; fm < 4; ++fm)
#pragma unroll
        for (int fn = 0; fn < 2; ++fn)
          acc[fm][fn] = __builtin_amdgcn_mfma_f32_16x16x32_bf16(af[fm], bf_[fn], acc[fm][fn], 0, 0, 0);
    }
    __syncthreads();
  }
#pragma unroll
  for (int fm = 0; fm < 4; ++fm)
#pragma unroll
    for (int qq = 0; qq < 4; ++qq) {
      int row = row0 + 16 * fm + 4 * hi + qq;
#pragma unroll
      for (int fn = 0; fn < 2; ++fn)
        C[(size_t)row * 1024 + col0 + 32 * w + 16 * fn + lo] = acc[fm][fn][qq];
    }
}

// ---------------- MFMA fused causal attention, split-bf16 inputs ----------------
// Persistent balanced schedule: 512 blocks, block i does items {1023-i, i}.
// T staged in a 192-SLOT ring: T(t+1)'s 64 new rows are issued at the START of
// compute(t) (their slots were last read at tile t-1; reads(t)=127 slots +
// writes=64 slots = 191 <= 192, disjoint) -> T staging latency hides under the
// whole MFMA phase instead of the ~100cyc stage gap. K hi/lo single-buffered
// via gload_lds in the bar1->bar2 gap. V reg-staged, double-XOR VSWZ. DPP
// rotate-reduce softmax, raw v_exp (q log2e-scaled), bf16-only output.
union U8 { uint4 q; unsigned short u[8]; };

__global__ __launch_bounds__(256, 2) void attn_kernel(
    const unsigned short* __restrict__ qhi, const unsigned short* __restrict__ qlo,
    const unsigned short* __restrict__ kvhi, const unsigned short* __restrict__ kvlo,
    const unsigned short* __restrict__ tabhi, const unsigned short* __restrict__ tablo,
    unsigned short* __restrict__ ohi) {
  __shared__ __align__(16) char sKhi[8192];   // K hi bf16 [64][64], swizzled
  __shared__ __align__(16) char sKlo[8192];   // K lo
  __shared__ __align__(16) char sT[49152];    // T ring: hi [0,24K) + lo [24K,48K), 192 slots
  __shared__ __align__(16) char sVT[8192];    // V^T bf16, VSWZ layout
  __shared__ __align__(16) char sP[8192];     // P bf16 [64 n][64 m], swizzled

  const int t = threadIdx.x;
  const int w = t >> 6;
  const int lane = t & 63;
  const int lo = lane & 15;
  const int hi = lane >> 4;

  for (int rep = 0; rep < 2; ++rep) {
    const int item = rep == 0 ? (1023 - (int)blockIdx.x) : (int)blockIdx.x;
    const int qb = item >> 5;
    const int z = (item >> 4) & 1;
    const int h = item & 15;
    const int n0 = qb * 64;

    __syncthreads();  // previous item's LDS readers done before prologue staging

    // ---- prologue: issue T(0) staging (127 rows + 1 pad row), load Q frags + V(0)
    {
#pragma unroll
      for (int it = 0; it < 4; ++it) {
        int f = it * 256 + t;
        int rr = f >> 3;                // 0..127
        int c = f & 7;
        int G = n0 + rr;                // g - R0TAB
        int grow = R0TAB + G;
        if (grow > RTAB - 1) grow = RTAB - 1;  // row 4095 clamp (never read)
        int slot = slot192(G);
        int gsw = (c ^ (G & 7)) << 3;
        size_t gb = (size_t)grow * DM + h * DH;
        gload_lds16(tabhi + gb + gsw, sT + slot * 128 + c * 16);
        gload_lds16(tablo + gb + gsw, sT + 24576 + slot * 128 + c * 16);
      }
    }

    // ---- Q fragments straight from split planes (already log2e-scaled)
    bf16x8 qh[2], ql[2];
    {
      size_t qoff = (size_t)((n0 + 16 * w + lo) * BZ + z) * DM + h * DH;
#pragma unroll
      for (int ks = 0; ks < 2; ++ks) {
        qh[ks] = *(const bf16x8*)(qhi + qoff + 32 * ks + 8 * hi);
        ql[ks] = *(const bf16x8*)(qlo + qoff + 32 * ks + 8 * hi);
      }
    }

    f32x4 accO[4];
#pragma unroll
    for (int f = 0; f < 4; ++f) accO[f] = (f32x4){0.f, 0.f, 0.f, 0.f};
    float mi[4], li[4];
#pragma unroll
    for (int qq = 0; qq < 4; ++qq) { mi[qq] = -1e30f; li[qq] = 0.f; }

    // V register staging (2 uint4 only)
    uint4 pVh[2];
#pragma unroll
    for (int it = 0; it < 2; ++it) {
      int f = it * 256 + t;
      int j = f >> 3;
      int d8 = (f & 7) << 3;
      size_t gb = (size_t)((0 + j) * BZ + z) * (NH * 2 * DH) + h * (2 * DH);
      pVh[it] = *(const uint4*)(kvhi + gb + DH + d8);
    }

    for (int mt = 0; mt <= qb; ++mt) {
      const int m0 = mt * 64;
      const int Wg = n0 - m0;  // window base minus R0TAB
      __syncthreads();  // bar1: prior tile's LDS reads complete before restaging

      // ---- async stage K hi/lo (pre-swizzled source -> linear LDS dest)
#pragma unroll
      for (int it = 0; it < 2; ++it) {
        int f = it * 256 + t;
        int j = f >> 3;
        int c = f & 7;
        int gsw = (c ^ (j & 7)) << 3;
        size_t gb = (size_t)((m0 + j) * BZ + z) * (NH * 2 * DH) + h * (2 * DH);
        gload_lds16(kvhi + gb + gsw, sKhi + f * 16);
        gload_lds16(kvlo + gb + gsw, sKlo + f * 16);
      }

      // ---- write this tile's V^T from regs (double-XOR VSWZ layout)
#pragma unroll
      for (int it = 0; it < 2; ++it) {
        int f = it * 256 + t;
        int j = f >> 3;
        int d8 = (f & 7) << 3;
        U8 vh;
        vh.q = pVh[it];
#pragma unroll
        for (int e = 0; e < 8; ++e) {
          int dv = d8 + e;
          *(unsigned short*)(sVT + VSWZ(dv, j)) = vh.u[e];
        }
      }
      // ---- issue next tile's V loads (land during this tile's compute)
      if (mt < qb) {
        const int m0n = (mt + 1) * 64;
#pragma unroll
        for (int it = 0; it < 2; ++it) {
          int f = it * 256 + t;
          int j = f >> 3;
          int d8 = (f & 7) << 3;
          size_t gb = (size_t)((m0n + j) * BZ + z) * (NH * 2 * DH) + h * (2 * DH);
          pVh[it] = *(const uint4*)(kvhi + gb + DH + d8);
        }
      }
      __syncthreads();  // bar2: drains gload_lds (K fresh; T issued a phase ago) + V^T writes

      // ---- EARLY-ISSUE T(t+1): 64 new rows into ring slots last read at t-1.
      // Disjoint from this tile's read slots; lands during the MFMA phase below.
      if (mt < qb) {
#pragma unroll
        for (int it = 0; it < 2; ++it) {
          int f = it * 256 + t;
          int rr = f >> 3;            // 0..63
          int c = f & 7;
          int Gn = Wg - 64 + rr;      // >= 0 since mt+1 <= qb
          int slot = slot192(Gn);
          int gsw = (c ^ (Gn & 7)) << 3;
          size_t gb = (size_t)(R0TAB + Gn) * DM + h * DH;
          gload_lds16(tabhi + gb + gsw, sT + slot * 128 + c * 16);
          gload_lds16(tablo + gb + gsw, sT + 24576 + slot * 128 + c * 16);
        }
      }

      // ---- S = QK^T and PL = QT^T, split-bf16 MFMA (T from ring slots)
      f32x4 accS[4], accPL[5];
#pragma unroll
      for (int f = 0; f < 4; ++f) accS[f] = (f32x4){0.f, 0.f, 0.f, 0.f};
#pragma unroll
      for (int f = 0; f < 5; ++f) accPL[f] = (f32x4){0.f, 0.f, 0.f, 0.f};
#pragma unroll
      for (int ks = 0; ks < 2; ++ks) {
#pragma unroll
        for (int fm = 0; fm < 4; ++fm) {
          int rb = SWZ(lo, (16 * fm + lo) * 128 + (32 * ks + 8 * hi) * 2);
          bf16x8 kh = *(const bf16x8*)(sKhi + rb);
          bf16x8 kl = *(const bf16x8*)(sKlo + rb);
          accS[fm] = __builtin_amdgcn_mfma_f32_16x16x32_bf16(qh[ks], kh, accS[fm], 0, 0, 0);
          accS[fm] = __builtin_amdgcn_mfma_f32_16x16x32_bf16(qh[ks], kl, accS[fm], 0, 0, 0);
          accS[fm] = __builtin_amdgcn_mfma_f32_16x16x32_bf16(ql[ks], kh, accS[fm], 0, 0, 0);
        }
#pragma unroll
        for (int fr = 0; fr < 5; ++fr) {
          int G = Wg + 16 * (w + fr) + lo;     // table row - R0TAB
          int rb = slot192(G) * 128 + (((4 * ks + hi) ^ (G & 7)) << 4);
          bf16x8 th = *(const bf16x8*)(sT + rb);
          bf16x8 tl = *(const bf16x8*)(sT + 24576 + rb);
          accPL[fr] = __builtin_amdgcn_mfma_f32_16x16x32_bf16(qh[ks], th, accPL[fr], 0, 0, 0);
          accPL[fr] = __builtin_amdgcn_mfma_f32_16x16x32_bf16(qh[ks], tl, accPL[fr], 0, 0, 0);
          accPL[fr] = __builtin_amdgcn_mfma_f32_16x16x32_bf16(ql[ks], th, accPL[fr], 0, 0, 0);
        }
      }

      // ---- PL diagonal gather, fully in-register via width-16 shuffles.
#pragma unroll
      for (int fm = 0; fm < 4; ++fm)
#pragma unroll
        for (int qq = 0; qq < 4; ++qq) {
          int rn = 4 * hi + qq + 63 - 16 * fm - lo;
          float va = __shfl(accPL[3 - fm][qq], rn & 15, 16);
          float vb = __shfl(accPL[4 - fm][qq], rn & 15, 16);
          accS[fm][qq] += (rn >> 4) == (3 - fm) ? va : vb;
        }

      if (mt == qb) {  // diagonal tile: mask m > n
#pragma unroll
        for (int fm = 0; fm < 4; ++fm)
#pragma unroll
          for (int qq = 0; qq < 4; ++qq)
            if (16 * fm + lo > 16 * w + 4 * hi + qq) accS[fm][qq] = -1e30f;
      }

      // ---- online softmax in registers (DPP rotate-reduce; raw v_exp)
#pragma unroll
      for (int qq = 0; qq < 4; ++qq) {
        float pm = fmaxf(fmaxf(accS[0][qq], accS[1][qq]), fmaxf(accS[2][qq], accS[3][qq]));
        pm = rowmax16(pm);
        float mn = fmaxf(mi[qq], pm);
        float a = fexp2(mi[qq] - mn);
        mi[qq] = mn;
        float rs = 0.f;
#pragma unroll
        for (int fm = 0; fm < 4; ++fm) {
          float p = fexp2(accS[fm][qq] - mn);
          accS[fm][qq] = p;
          rs += p;
        }
        rs = rowsum16(rs);
        li[qq] = li[qq] * a + rs;
#pragma unroll
        for (int f = 0; f < 4; ++f) accO[f][qq] *= a;
      }

      // ---- P -> LDS bf16 (wave-local rows)
#pragma unroll
      for (int fm = 0; fm < 4; ++fm)
#pragma unroll
        for (int qq = 0; qq < 4; ++qq) {
          int row = 16 * w + 4 * hi + qq;
          *(unsigned short*)(sP + SWZ(4 * hi + qq, row * 128 + (16 * fm + lo) * 2)) =
              f2bf(accS[fm][qq]);
        }

      // ---- PV: accO += P @ V
#pragma unroll
      for (int ks = 0; ks < 2; ++ks) {
        int ab = SWZ(lo, (16 * w + lo) * 128 + (32 * ks + 8 * hi) * 2);
        bf16x8 pa = *(const bf16x8*)(sP + ab);
#pragma unroll
        for (int fv = 0; fv < 4; ++fv) {
          int dv = 16 * fv + lo;
          int vb = dv * 128 + ((((4 * ks + hi) ^ (dv & 7) ^ ((dv >> 3) & 7))) << 4);
          bf16x8 vv = *(const bf16x8*)(sVT + vb);
          accO[fv] = __builtin_amdgcn_mfma_f32_16x16x32_bf16(pa, vv, accO[fv], 0, 0, 0);
        }
      }
    }

    // ---- epilogue: attn = accO / li, bf16 (hi plane only)
#pragma unroll
    for (int qq = 0; qq < 4; ++qq) {
      float inv = 1.0f / li[qq];
      int n = n0 + 16 * w + 4 * hi + qq;
#pragma unroll
      for (int fv = 0; fv < 4; ++fv) {
        size_t idx = (size_t)(n * BZ + z) * DM + h * DH + 16 * fv + lo;
        ohi[idx] = f2bf(accO[fv][qq] * inv);
      }
    }
  }
}

// ---------------- launch ----------------
extern "C" void kernel_launch(void* const* d_in, const int* in_sizes, int n_in,
                              void* d_out, int out_size, void* d_ws, size_t ws_size,
                              hipStream_t stream) {
  const float* x_q   = (const float*)d_in[0];
  const float* x_kv  = (const float*)d_in[1];
  const float* to_q  = (const float*)d_in[2];
  const float* to_kv = (const float*)d_in[3];
  const float* fpe   = (const float*)d_in[4];
  const float* to_o  = (const float*)d_in[5];
  float* out = (float*)d_out;

  char* W = (char*)d_ws;
  size_t o = 0;
  auto alloc = [&](size_t bytes) { char* p = W + o; o += (bytes + 255) & ~(size_t)255; return p; };
  typedef unsigned short us;
  us* q_hi  = (us*)alloc((size_t)4096 * 1024 * 2);
  us* q_lo  = (us*)alloc((size_t)4096 * 1024 * 2);
  us* kv_hi = (us*)alloc((size_t)4096 * 2048 * 2);
  us* kv_lo = (us*)alloc((size_t)4096 * 2048 * 2);
  us* tab_hi = (us*)alloc((size_t)RTAB * 1024 * 2);
  us* tab_lo = (us*)alloc((size_t)RTAB * 1024 * 2);
  us* xq_hi = (us*)alloc((size_t)4096 * 1024 * 2);
  us* xq_lo = (us*)alloc((size_t)4096 * 1024 * 2);
  us* xkv_hi = (us*)alloc((size_t)4096 * 1024 * 2); // later: attn-out hi
  us* xkv_lo = (us*)alloc((size_t)4096 * 1024 * 2);
  us* tq_hi  = (us*)alloc((size_t)1024 * 1024 * 2);
  us* tq_lo  = (us*)alloc((size_t)1024 * 1024 * 2);
  us* tkv_hi = (us*)alloc((size_t)2048 * 1024 * 2);
  us* tkv_lo = (us*)alloc((size_t)2048 * 1024 * 2);
  us* to_hi  = (us*)alloc((size_t)1024 * 1024 * 2);
  us* to_lo  = (us*)alloc((size_t)1024 * 1024 * 2);
  us* fpe_hi = (us*)alloc((size_t)1024 * 1024 * 2);
  us* fpe_lo = (us*)alloc((size_t)1024 * 1024 * 2);
  us* sc_hi  = (us*)alloc((size_t)MTAB * 1024 * 2);
  us* sc_lo  = (us*)alloc((size_t)MTAB * 1024 * 2);

  // 1. fused prep: split all 6 inputs + sincos table (one launch)
  prep_kernel<<<dim3(4096, 7), 256, 0, stream>>>(
      x_q,   xq_hi,  xq_lo,  4096 * 1024 / 4,
      x_kv,  xkv_hi, xkv_lo, 4096 * 1024 / 4,
      to_q,  tq_hi,  tq_lo,  1024 * 1024 / 4,
      to_kv, tkv_hi, tkv_lo, 2048 * 1024 / 4,
      to_o,  to_hi,  to_lo,  1024 * 1024 / 4,
      fpe,   fpe_hi, fpe_lo, 1024 * 1024 / 4,
      sc_hi, sc_lo);

  // 2. fused 3-GEMM: q (log2e-scaled) + kv + tab (904 blocks, one launch)
  gemm3_kernel<<<dim3(904), 256, 0, stream>>>(
      xq_hi, xq_lo, tq_hi, tq_lo, q_hi, q_lo,
      xkv_hi, xkv_lo, tkv_hi, tkv_lo, kv_hi, kv_lo,
      sc_hi, sc_lo, fpe_hi, fpe_lo,
      tab_hi + (size_t)R0TAB * 1024, tab_lo + (size_t)R0TAB * 1024);

  // 3. fused attention (balanced persistent grid, 192-ring early-issue T) -> bf16
  us* at_hi = xkv_hi;
  attn_kernel<<<dim3(512), 256, 0, stream>>>(q_hi, q_lo, kv_hi, kv_lo,
                                             tab_hi, tab_lo, at_hi);
  // 4. out = attn @ to_o^T -> fp32 (plain bf16 MFMA, 64x128 tiles, 512 blocks)
  gemm_out_kernel<<<dim3(8, 64), 256, 0, stream>>>(at_hi, to_hi, out);
}

// Round 17
// 230.040 us; speedup vs baseline: 1.0360x; 1.0360x over previous
//
#include <hip/hip_runtime.h>
#include <math.h>

#define NQ 2048
#define MKV 2048
#define BZ 2
#define DM 1024
#define NH 16
#define DH 64
#define RTAB 4095  /* NQ + MKV - 1 */
#define R0TAB 1984 /* lowest table row reachable under causal mask */
#define MTAB (RTAB - R0TAB) /* 2111 */
#define LOG2E 1.44269504088896340736f

typedef __bf16 bf16x8 __attribute__((ext_vector_type(8)));
typedef float f32x4 __attribute__((ext_vector_type(4)));

// native f32->bf16 (single v_cvt; lo plane captures the residual of whatever hi rounds to)
__device__ inline unsigned short f2bf(float x) {
  __bf16 b = (__bf16)x;
  union { __bf16 b; unsigned short u; } v; v.b = b; return v.u;
}
__device__ inline float bf2f(unsigned short h) {
  union { unsigned u; float f; } v; v.u = ((unsigned)h) << 16; return v.f;
}
// raw v_exp_f32 (D = 2^S0)
__device__ inline float fexp2(float x) { return __builtin_amdgcn_exp2f(x); }

// DPP row_ror:N within 16-lane rows (VALU pipe, not LDS)
template <int N>
__device__ inline float ror16(float x) {
  union { float f; int i; } a, r;
  a.f = x;
  r.i = __builtin_amdgcn_mov_dpp(a.i, 0x120 | N, 0xf, 0xf, true);
  return r.f;
}
__device__ inline float rowmax16(float x) {
  x = fmaxf(x, ror16<1>(x));
  x = fmaxf(x, ror16<2>(x));
  x = fmaxf(x, ror16<4>(x));
  x = fmaxf(x, ror16<8>(x));
  return x;
}
__device__ inline float rowsum16(float x) {
  x += ror16<1>(x);
  x += ror16<2>(x);
  x += ror16<4>(x);
  x += ror16<8>(x);
  return x;
}

#define SWZ(r, b) ((b) ^ (((r) & 7) << 4))
// V^T layout, conflict-free on BOTH b16 scatter-write and b128 read
#define VSWZ(dv, m) \
  ((dv) * 128 + (((((m) >> 3) ^ ((dv) & 7) ^ (((dv) >> 3) & 7)) << 4)) + ((m) & 7) * 2)

__device__ inline void gload_lds16(const void* g, void* l) {
  __builtin_amdgcn_global_load_lds((const __attribute__((address_space(1))) void*)g,
                                   (__attribute__((address_space(3))) void*)l, 16, 0, 0);
}

// ---------------- fused prep: fp32->(hi,lo) split for 6 inputs + sincos table ----------------
__global__ __launch_bounds__(256) void prep_kernel(
    const float* __restrict__ i0, unsigned short* __restrict__ h0, unsigned short* __restrict__ l0, int n0,
    const float* __restrict__ i1, unsigned short* __restrict__ h1, unsigned short* __restrict__ l1, int n1,
    const float* __restrict__ i2, unsigned short* __restrict__ h2, unsigned short* __restrict__ l2, int n2,
    const float* __restrict__ i3, unsigned short* __restrict__ h3, unsigned short* __restrict__ l3, int n3,
    const float* __restrict__ i4, unsigned short* __restrict__ h4, unsigned short* __restrict__ l4, int n4_,
    const float* __restrict__ i5, unsigned short* __restrict__ h5, unsigned short* __restrict__ l5, int n5,
    unsigned short* __restrict__ schi, unsigned short* __restrict__ sclo) {
  if (blockIdx.y == 6) {
    for (int idx = blockIdx.x * 256 + threadIdx.x; idx < MTAB * DM; idx += gridDim.x * 256) {
      int r = idx / DM;
      int b = idx - r * DM;
      int i = (b < DM / 2) ? b : (b - DM / 2);
      double fr = exp((double)i * (-9.210340371976184 / 512.0));
      float rr = (float)(R0TAB + r - (MKV - 1));
      float ph = rr * (float)fr;
      float val = (b < DM / 2) ? sinf(ph) : cosf(ph);
      unsigned short hb = f2bf(val);
      schi[idx] = hb;
      sclo[idx] = f2bf(val - bf2f(hb));
    }
    return;
  }
  const float* in; unsigned short* hp; unsigned short* lp; int n4;
  switch (blockIdx.y) {
    case 0: in = i0; hp = h0; lp = l0; n4 = n0; break;
    case 1: in = i1; hp = h1; lp = l1; n4 = n1; break;
    case 2: in = i2; hp = h2; lp = l2; n4 = n2; break;
    case 3: in = i3; hp = h3; lp = l3; n4 = n3; break;
    case 4: in = i4; hp = h4; lp = l4; n4 = n4_; break;
    default: in = i5; hp = h5; lp = l5; n4 = n5; break;
  }
  for (int i = blockIdx.x * 256 + threadIdx.x; i < n4; i += gridDim.x * 256) {
    float4 v = ((const float4*)in)[i];
    float f[4] = {v.x, v.y, v.z, v.w};
    ushort4 hq, lq;
    unsigned short* hh = (unsigned short*)&hq;
    unsigned short* ll = (unsigned short*)&lq;
#pragma unroll
    for (int e = 0; e < 4; ++e) {
      unsigned short hb = f2bf(f[e]);
      hh[e] = hb;
      ll[e] = f2bf(f[e] - bf2f(hb));
    }
    ((ushort4*)hp)[i] = hq;
    ((ushort4*)lp)[i] = lq;
  }
}

// ---------------- split-bf16 MFMA NT GEMM body (K = 1024 fixed) ----------------
// KVSKIP: wn==1 half computes V columns (head-aligned tiles) -> hi*hi MFMA only,
// skip al/bl fragment reads, skip lo-plane stores, skip sBl staging rows 64..127.
template <int SPLIT_OUT, int KVSKIP>
__device__ __forceinline__ void gemm_body(
    const unsigned short* __restrict__ Ahi, const unsigned short* __restrict__ Alo,
    const unsigned short* __restrict__ Bhi, const unsigned short* __restrict__ Blo,
    float* __restrict__ Cf, unsigned short* __restrict__ Chi, unsigned short* __restrict__ Clo,
    int M, int N, int row0, int col0, char* lds, float cscale) {
  const int K = 1024;
  char* sAh = lds;
  char* sAl = lds + 16384;
  char* sBh = lds + 32768;
  char* sBl = lds + 49152;
  const int t = threadIdx.x;
  const int w = t >> 6;
  const int lane = t & 63;
  const int lo = lane & 15;
  const int hi = lane >> 4;
  const int wm = w >> 1, wn = w & 1;

  f32x4 acc[4][4];
#pragma unroll
  for (int a = 0; a < 4; ++a)
#pragma unroll
    for (int b = 0; b < 4; ++b) acc[a][b] = (f32x4){0.f, 0.f, 0.f, 0.f};

  for (int k0 = 0; k0 < K; k0 += 64) {
#pragma unroll
    for (int i = 0; i < 4; ++i) {
      int L = i * 4096 + t * 16;
      int r = L >> 7;
      int c16 = (L >> 4) & 7;
      int g16 = c16 ^ (r & 7);
      int ra = row0 + r;
      if (ra >= M) ra = M - 1;
      int rb = col0 + r;
      const char* gah = (const char*)(Ahi + (size_t)ra * K + k0) + g16 * 16;
      const char* gal = (const char*)(Alo + (size_t)ra * K + k0) + g16 * 16;
      const char* gbh = (const char*)(Bhi + (size_t)rb * K + k0) + g16 * 16;
      const char* gbl = (const char*)(Blo + (size_t)rb * K + k0) + g16 * 16;
      gload_lds16(gah, sAh + L);
      gload_lds16(gal, sAl + L);
      gload_lds16(gbh, sBh + L);
      if (!KVSKIP || i < 2)  // sBl rows 64..127 never read when KVSKIP
        gload_lds16(gbl, sBl + L);
    }
    __syncthreads();
#pragma unroll
    for (int ks = 0; ks < 2; ++ks) {
      bf16x8 ah[4], al[4], bh[4], bl[4];
#pragma unroll
      for (int f = 0; f < 4; ++f) {
        int rA = wm * 64 + 16 * f + lo;
        int offA = rA * 128 + (((4 * ks + hi) ^ (rA & 7)) << 4);
        ah[f] = *(const bf16x8*)(sAh + offA);
        int rB = wn * 64 + 16 * f + lo;
        int offB = rB * 128 + (((4 * ks + hi) ^ (rB & 7)) << 4);
        bh[f] = *(const bf16x8*)(sBh + offB);
        if (!KVSKIP || wn == 0) {
          al[f] = *(const bf16x8*)(sAl + offA);
          bl[f] = *(const bf16x8*)(sBl + offB);
        }
      }
      if (KVSKIP && wn == 1) {
#pragma unroll
        for (int fm = 0; fm < 4; ++fm)
#pragma unroll
          for (int fn = 0; fn < 4; ++fn)
            acc[fm][fn] = __builtin_amdgcn_mfma_f32_16x16x32_bf16(ah[fm], bh[fn], acc[fm][fn], 0, 0, 0);
      } else {
#pragma unroll
        for (int fm = 0; fm < 4; ++fm)
#pragma unroll
          for (int fn = 0; fn < 4; ++fn) {
            acc[fm][fn] = __builtin_amdgcn_mfma_f32_16x16x32_bf16(ah[fm], bh[fn], acc[fm][fn], 0, 0, 0);
            acc[fm][fn] = __builtin_amdgcn_mfma_f32_16x16x32_bf16(ah[fm], bl[fn], acc[fm][fn], 0, 0, 0);
            acc[fm][fn] = __builtin_amdgcn_mfma_f32_16x16x32_bf16(al[fm], bh[fn], acc[fm][fn], 0, 0, 0);
          }
      }
    }
    __syncthreads();
  }
  // epilogue
#pragma unroll
  for (int fm = 0; fm < 4; ++fm)
#pragma unroll
    for (int qq = 0; qq < 4; ++qq) {
      int row = row0 + wm * 64 + 16 * fm + 4 * hi + qq;
      if (row < M) {
#pragma unroll
        for (int fn = 0; fn < 4; ++fn) {
          int col = col0 + wn * 64 + 16 * fn + lo;
          float v = acc[fm][fn][qq] * cscale;
          if (SPLIT_OUT) {
            unsigned short hb = f2bf(v);
            Chi[(size_t)row * N + col] = hb;
            if (!KVSKIP || wn == 0)
              Clo[(size_t)row * N + col] = f2bf(v - bf2f(hb));
          } else {
            Cf[(size_t)row * N + col] = v;
          }
        }
      }
    }
}

// ---------------- fused 3-GEMM dispatch: q(256 blk) + kv(512 blk) + tab(136 blk) ----------------
__global__ __launch_bounds__(256, 2) void gemm3_kernel(
    const unsigned short* __restrict__ xqh, const unsigned short* __restrict__ xql,
    const unsigned short* __restrict__ tqh, const unsigned short* __restrict__ tql,
    unsigned short* __restrict__ qh, unsigned short* __restrict__ ql,
    const unsigned short* __restrict__ xkh, const unsigned short* __restrict__ xkl,
    const unsigned short* __restrict__ tkh, const unsigned short* __restrict__ tkl,
    unsigned short* __restrict__ kvh, unsigned short* __restrict__ kvl,
    const unsigned short* __restrict__ sch, const unsigned short* __restrict__ scl,
    const unsigned short* __restrict__ fph, const unsigned short* __restrict__ fpl,
    unsigned short* __restrict__ tbh, unsigned short* __restrict__ tbl) {
  __shared__ char lds[65536];
  int bx = blockIdx.x;
  if (bx < 256) {        // q = x_q @ to_q^T : scaled by log2e (q feeds only logits)
    int gx = bx & 7, gy = bx >> 3;
    gemm_body<1, 0>(xqh, xql, tqh, tql, nullptr, qh, ql, 4096, 1024, gy * 128, gx * 128, lds, LOG2E);
  } else if (bx < 768) { // kv = x_kv @ to_kv^T (V-column half: hi*hi only)
    bx -= 256;
    int gx = bx & 15, gy = bx >> 4;
    gemm_body<1, 1>(xkh, xkl, tkh, tkl, nullptr, kvh, kvl, 4096, 2048, gy * 128, gx * 128, lds, 1.0f);
  } else {               // tab = sincos @ fpe^T
    bx -= 768;
    int gx = bx & 7, gy = bx >> 3;
    gemm_body<1, 0>(sch, scl, fph, fpl, nullptr, tbh, tbl, MTAB, 1024, gy * 128, gx * 128, lds, 1.0f);
  }
}

// ---------------- out GEMM: plain bf16, 64x128 tile (512 blocks) ----------------
__global__ __launch_bounds__(256, 2) void gemm_out_kernel(
    const unsigned short* __restrict__ A,   // at_hi [4096][1024]
    const unsigned short* __restrict__ B,   // to_hi [1024][1024]
    float* __restrict__ C) {
  __shared__ __align__(16) char sA[8192];
  __shared__ __align__(16) char sB[16384];
  const int t = threadIdx.x;
  const int w = t >> 6;
  const int lane = t & 63;
  const int lo = lane & 15;
  const int hi = lane >> 4;
  const int row0 = blockIdx.y * 64;
  const int col0 = blockIdx.x * 128;

  f32x4 acc[4][2];
#pragma unroll
  for (int a = 0; a < 4; ++a)
#pragma unroll
    for (int b = 0; b < 2; ++b) acc[a][b] = (f32x4){0.f, 0.f, 0.f, 0.f};

  for (int k0 = 0; k0 < 1024; k0 += 64) {
#pragma unroll
    for (int it = 0; it < 2; ++it) {
      int f = it * 256 + t;
      int r = f >> 3;
      int c = f & 7;
      int g16 = c ^ (r & 7);
      gload_lds16(A + (size_t)(row0 + r) * 1024 + k0 + g16 * 8, sA + f * 16);
    }
#pragma unroll
    for (int it = 0; it < 4; ++it) {
      int f = it * 256 + t;
      int r = f >> 3;
      int c = f & 7;
      int g16 = c ^ (r & 7);
      gload_lds16(B + (size_t)(col0 + r) * 1024 + k0 + g16 * 8, sB + f * 16);
    }
    __syncthreads();
#pragma unroll
    for (int ks = 0; ks < 2; ++ks) {
      bf16x8 af[4], bf_[2];
#pragma unroll
      for (int f = 0; f < 4; ++f) {
        int rA = 16 * f + lo;
        af[f] = *(const bf16x8*)(sA + rA * 128 + (((4 * ks + hi) ^ (rA & 7)) << 4));
      }
#pragma unroll
      for (int f = 0; f < 2; ++f) {
        int rB = 32 * w + 16 * f + lo;
        bf_[f] = *(const bf16x8*)(sB + rB * 128 + (((4 * ks + hi) ^ (rB & 7)) << 4));
      }
#pragma unroll
      for (int fm = 0; fm < 4; ++fm)
#pragma unroll
        for (int fn = 0; fn < 2; ++fn)
          acc[fm][fn] = __builtin_amdgcn_mfma_f32_16x16x32_bf16(af[fm], bf_[fn], acc[fm][fn], 0, 0, 0);
    }
    __syncthreads();
  }
#pragma unroll
  for (int fm = 0; fm < 4; ++fm)
#pragma unroll
    for (int qq = 0; qq < 4; ++qq) {
      int row = row0 + 16 * fm + 4 * hi + qq;
#pragma unroll
      for (int fn = 0; fn < 2; ++fn)
        C[(size_t)row * 1024 + col0 + 32 * w + 16 * fn + lo] = acc[fm][fn][qq];
    }
}

// ---------------- MFMA fused causal attention (R15 structure, unchanged) ----------------
union U8 { uint4 q; unsigned short u[8]; };

__global__ __launch_bounds__(256, 2) void attn_kernel(
    const unsigned short* __restrict__ qhi, const unsigned short* __restrict__ qlo,
    const unsigned short* __restrict__ kvhi, const unsigned short* __restrict__ kvlo,
    const unsigned short* __restrict__ tabhi, const unsigned short* __restrict__ tablo,
    unsigned short* __restrict__ ohi) {
  __shared__ __align__(16) char sKhi[8192];   // K hi bf16 [64][64], swizzled
  __shared__ __align__(16) char sKlo[8192];   // K lo
  __shared__ __align__(16) char sT[32768];    // T ring: hi [0,16K) + lo [16K,32K)
  __shared__ __align__(16) char sVT[8192];    // V^T bf16, VSWZ layout
  __shared__ __align__(16) char sP[8192];     // P bf16 [64 n][64 m], swizzled

  const int t = threadIdx.x;
  const int w = t >> 6;
  const int lane = t & 63;
  const int lo = lane & 15;
  const int hi = lane >> 4;

  for (int rep = 0; rep < 2; ++rep) {
    const int item = rep == 0 ? (1023 - (int)blockIdx.x) : (int)blockIdx.x;
    const int qb = item >> 5;
    const int z = (item >> 4) & 1;
    const int h = item & 15;
    const int n0 = qb * 64;

    // ---- Q fragments straight from split planes (already log2e-scaled)
    bf16x8 qh[2], ql[2];
    {
      size_t qoff = (size_t)((n0 + 16 * w + lo) * BZ + z) * DM + h * DH;
#pragma unroll
      for (int ks = 0; ks < 2; ++ks) {
        qh[ks] = *(const bf16x8*)(qhi + qoff + 32 * ks + 8 * hi);
        ql[ks] = *(const bf16x8*)(qlo + qoff + 32 * ks + 8 * hi);
      }
    }

    f32x4 accO[4];
#pragma unroll
    for (int f = 0; f < 4; ++f) accO[f] = (f32x4){0.f, 0.f, 0.f, 0.f};
    float mi[4], li[4];
#pragma unroll
    for (int qq = 0; qq < 4; ++qq) { mi[qq] = -1e30f; li[qq] = 0.f; }

    // V register staging (2 uint4 only)
    uint4 pVh[2];
#pragma unroll
    for (int it = 0; it < 2; ++it) {
      int f = it * 256 + t;
      int j = f >> 3;
      int d8 = (f & 7) << 3;
      size_t gb = (size_t)((0 + j) * BZ + z) * (NH * 2 * DH) + h * (2 * DH);
      pVh[it] = *(const uint4*)(kvhi + gb + DH + d8);
    }

    for (int mt = 0; mt <= qb; ++mt) {
      const int m0 = mt * 64;
      const int Wb = n0 - m0 + R0TAB;  // window base (global table row)
      __syncthreads();  // prior tile's LDS reads complete before restaging

      // ---- async stage K hi/lo (pre-swizzled source -> linear LDS dest)
#pragma unroll
      for (int it = 0; it < 2; ++it) {
        int f = it * 256 + t;
        int j = f >> 3;
        int c = f & 7;
        int gsw = (c ^ (j & 7)) << 3;
        size_t gb = (size_t)((m0 + j) * BZ + z) * (NH * 2 * DH) + h * (2 * DH);
        gload_lds16(kvhi + gb + gsw, sKhi + f * 16);
        gload_lds16(kvlo + gb + gsw, sKlo + f * 16);
      }
      // ---- async stage T ring: mt==0 full 128 rows, else only 64 new rows
      if (mt == 0) {
#pragma unroll
        for (int it = 0; it < 4; ++it) {
          int f = it * 256 + t;
          int rr = f >> 3;
          int c = f & 7;
          int g = Wb + rr;
          int gc = g < RTAB ? g : (RTAB - 1);
          int slot = g & 127;
          int gsw = (c ^ (g & 7)) << 3;
          size_t gb = (size_t)gc * DM + h * DH;
          gload_lds16(tabhi + gb + gsw, sT + slot * 128 + c * 16);
          gload_lds16(tablo + gb + gsw, sT + 16384 + slot * 128 + c * 16);
        }
      } else {
#pragma unroll
        for (int it = 0; it < 2; ++it) {
          int f = it * 256 + t;
          int rr = f >> 3;
          int c = f & 7;
          int g = Wb + rr;
          int slot = g & 127;
          int gsw = (c ^ (g & 7)) << 3;
          size_t gb = (size_t)g * DM + h * DH;
          gload_lds16(tabhi + gb + gsw, sT + slot * 128 + c * 16);
          gload_lds16(tablo + gb + gsw, sT + 16384 + slot * 128 + c * 16);
        }
      }

      // ---- write this tile's V^T from regs (double-XOR VSWZ layout)
#pragma unroll
      for (int it = 0; it < 2; ++it) {
        int f = it * 256 + t;
        int j = f >> 3;
        int d8 = (f & 7) << 3;
        U8 vh;
        vh.q = pVh[it];
#pragma unroll
        for (int e = 0; e < 8; ++e) {
          int dv = d8 + e;
          *(unsigned short*)(sVT + VSWZ(dv, j)) = vh.u[e];
        }
      }
      // ---- issue next tile's V loads (land during this tile's compute)
      if (mt < qb) {
        const int m0n = (mt + 1) * 64;
#pragma unroll
        for (int it = 0; it < 2; ++it) {
          int f = it * 256 + t;
          int j = f >> 3;
          int d8 = (f & 7) << 3;
          size_t gb = (size_t)((m0n + j) * BZ + z) * (NH * 2 * DH) + h * (2 * DH);
          pVh[it] = *(const uint4*)(kvhi + gb + DH + d8);
        }
      }
      __syncthreads();  // drains gload_lds (vmcnt) + V^T ds writes

      // ---- S = QK^T and PL = QT^T, split-bf16 MFMA (T from ring slots)
      f32x4 accS[4], accPL[5];
#pragma unroll
      for (int f = 0; f < 4; ++f) accS[f] = (f32x4){0.f, 0.f, 0.f, 0.f};
#pragma unroll
      for (int f = 0; f < 5; ++f) accPL[f] = (f32x4){0.f, 0.f, 0.f, 0.f};
#pragma unroll
      for (int ks = 0; ks < 2; ++ks) {
#pragma unroll
        for (int fm = 0; fm < 4; ++fm) {
          int rb = SWZ(lo, (16 * fm + lo) * 128 + (32 * ks + 8 * hi) * 2);
          bf16x8 kh = *(const bf16x8*)(sKhi + rb);
          bf16x8 kl = *(const bf16x8*)(sKlo + rb);
          accS[fm] = __builtin_amdgcn_mfma_f32_16x16x32_bf16(qh[ks], kh, accS[fm], 0, 0, 0);
          accS[fm] = __builtin_amdgcn_mfma_f32_16x16x32_bf16(qh[ks], kl, accS[fm], 0, 0, 0);
          accS[fm] = __builtin_amdgcn_mfma_f32_16x16x32_bf16(ql[ks], kh, accS[fm], 0, 0, 0);
        }
#pragma unroll
        for (int fr = 0; fr < 5; ++fr) {
          int g = Wb + 16 * (w + fr) + lo;
          int rb = (g & 127) * 128 + (((4 * ks + hi) ^ (g & 7)) << 4);
          bf16x8 th = *(const bf16x8*)(sT + rb);
          bf16x8 tl = *(const bf16x8*)(sT + 16384 + rb);
          accPL[fr] = __builtin_amdgcn_mfma_f32_16x16x32_bf16(qh[ks], th, accPL[fr], 0, 0, 0);
          accPL[fr] = __builtin_amdgcn_mfma_f32_16x16x32_bf16(qh[ks], tl, accPL[fr], 0, 0, 0);
          accPL[fr] = __builtin_amdgcn_mfma_f32_16x16x32_bf16(ql[ks], th, accPL[fr], 0, 0, 0);
        }
      }

      // ---- PL diagonal gather, fully in-register via width-16 shuffles.
#pragma unroll
      for (int fm = 0; fm < 4; ++fm)
#pragma unroll
        for (int qq = 0; qq < 4; ++qq) {
          int rn = 4 * hi + qq + 63 - 16 * fm - lo;
          float va = __shfl(accPL[3 - fm][qq], rn & 15, 16);
          float vb = __shfl(accPL[4 - fm][qq], rn & 15, 16);
          accS[fm][qq] += (rn >> 4) == (3 - fm) ? va : vb;
        }

      if (mt == qb) {  // diagonal tile: mask m > n
#pragma unroll
        for (int fm = 0; fm < 4; ++fm)
#pragma unroll
          for (int qq = 0; qq < 4; ++qq)
            if (16 * fm + lo > 16 * w + 4 * hi + qq) accS[fm][qq] = -1e30f;
      }

      // ---- online softmax in registers (DPP rotate-reduce; raw v_exp)
#pragma unroll
      for (int qq = 0; qq < 4; ++qq) {
        float pm = fmaxf(fmaxf(accS[0][qq], accS[1][qq]), fmaxf(accS[2][qq], accS[3][qq]));
        pm = rowmax16(pm);
        float mn = fmaxf(mi[qq], pm);
        float a = fexp2(mi[qq] - mn);
        mi[qq] = mn;
        float rs = 0.f;
#pragma unroll
        for (int fm = 0; fm < 4; ++fm) {
          float p = fexp2(accS[fm][qq] - mn);
          accS[fm][qq] = p;
          rs += p;
        }
        rs = rowsum16(rs);
        li[qq] = li[qq] * a + rs;
#pragma unroll
        for (int f = 0; f < 4; ++f) accO[f][qq] *= a;
      }

      // ---- P -> LDS bf16 (wave-local rows)
#pragma unroll
      for (int fm = 0; fm < 4; ++fm)
#pragma unroll
        for (int qq = 0; qq < 4; ++qq) {
          int row = 16 * w + 4 * hi + qq;
          *(unsigned short*)(sP + SWZ(4 * hi + qq, row * 128 + (16 * fm + lo) * 2)) =
              f2bf(accS[fm][qq]);
        }

      // ---- PV: accO += P @ V
#pragma unroll
      for (int ks = 0; ks < 2; ++ks) {
        int ab = SWZ(lo, (16 * w + lo) * 128 + (32 * ks + 8 * hi) * 2);
        bf16x8 pa = *(const bf16x8*)(sP + ab);
#pragma unroll
        for (int fv = 0; fv < 4; ++fv) {
          int dv = 16 * fv + lo;
          int vb = dv * 128 + ((((4 * ks + hi) ^ (dv & 7) ^ ((dv >> 3) & 7))) << 4);
          bf16x8 vv = *(const bf16x8*)(sVT + vb);
          accO[fv] = __builtin_amdgcn_mfma_f32_16x16x32_bf16(pa, vv, accO[fv], 0, 0, 0);
        }
      }
    }

    // ---- epilogue: attn = accO / li, bf16 (hi plane only)
#pragma unroll
    for (int qq = 0; qq < 4; ++qq) {
      float inv = 1.0f / li[qq];
      int n = n0 + 16 * w + 4 * hi + qq;
#pragma unroll
      for (int fv = 0; fv < 4; ++fv) {
        size_t idx = (size_t)(n * BZ + z) * DM + h * DH + 16 * fv + lo;
        ohi[idx] = f2bf(accO[fv][qq] * inv);
      }
    }
  }
}

// ---------------- launch ----------------
extern "C" void kernel_launch(void* const* d_in, const int* in_sizes, int n_in,
                              void* d_out, int out_size, void* d_ws, size_t ws_size,
                              hipStream_t stream) {
  const float* x_q   = (const float*)d_in[0];
  const float* x_kv  = (const float*)d_in[1];
  const float* to_q  = (const float*)d_in[2];
  const float* to_kv = (const float*)d_in[3];
  const float* fpe   = (const float*)d_in[4];
  const float* to_o  = (const float*)d_in[5];
  float* out = (float*)d_out;

  char* W = (char*)d_ws;
  size_t o = 0;
  auto alloc = [&](size_t bytes) { char* p = W + o; o += (bytes + 255) & ~(size_t)255; return p; };
  typedef unsigned short us;
  us* q_hi  = (us*)alloc((size_t)4096 * 1024 * 2);
  us* q_lo  = (us*)alloc((size_t)4096 * 1024 * 2);
  us* kv_hi = (us*)alloc((size_t)4096 * 2048 * 2);
  us* kv_lo = (us*)alloc((size_t)4096 * 2048 * 2);
  us* tab_hi = (us*)alloc((size_t)RTAB * 1024 * 2);
  us* tab_lo = (us*)alloc((size_t)RTAB * 1024 * 2);
  us* xq_hi = (us*)alloc((size_t)4096 * 1024 * 2);
  us* xq_lo = (us*)alloc((size_t)4096 * 1024 * 2);
  us* xkv_hi = (us*)alloc((size_t)4096 * 1024 * 2); // later: attn-out hi
  us* xkv_lo = (us*)alloc((size_t)4096 * 1024 * 2);
  us* tq_hi  = (us*)alloc((size_t)1024 * 1024 * 2);
  us* tq_lo  = (us*)alloc((size_t)1024 * 1024 * 2);
  us* tkv_hi = (us*)alloc((size_t)2048 * 1024 * 2);
  us* tkv_lo = (us*)alloc((size_t)2048 * 1024 * 2);
  us* to_hi  = (us*)alloc((size_t)1024 * 1024 * 2);
  us* to_lo  = (us*)alloc((size_t)1024 * 1024 * 2);
  us* fpe_hi = (us*)alloc((size_t)1024 * 1024 * 2);
  us* fpe_lo = (us*)alloc((size_t)1024 * 1024 * 2);
  us* sc_hi  = (us*)alloc((size_t)MTAB * 1024 * 2);
  us* sc_lo  = (us*)alloc((size_t)MTAB * 1024 * 2);

  // 1. fused prep: split all 6 inputs + sincos table (one launch)
  prep_kernel<<<dim3(4096, 7), 256, 0, stream>>>(
      x_q,   xq_hi,  xq_lo,  4096 * 1024 / 4,
      x_kv,  xkv_hi, xkv_lo, 4096 * 1024 / 4,
      to_q,  tq_hi,  tq_lo,  1024 * 1024 / 4,
      to_kv, tkv_hi, tkv_lo, 2048 * 1024 / 4,
      to_o,  to_hi,  to_lo,  1024 * 1024 / 4,
      fpe,   fpe_hi, fpe_lo, 1024 * 1024 / 4,
      sc_hi, sc_lo);

  // 2. fused 3-GEMM: q (log2e-scaled) + kv (V hi-only) + tab (904 blocks)
  gemm3_kernel<<<dim3(904), 256, 0, stream>>>(
      xq_hi, xq_lo, tq_hi, tq_lo, q_hi, q_lo,
      xkv_hi, xkv_lo, tkv_hi, tkv_lo, kv_hi, kv_lo,
      sc_hi, sc_lo, fpe_hi, fpe_lo,
      tab_hi + (size_t)R0TAB * 1024, tab_lo + (size_t)R0TAB * 1024);

  // 3. fused attention (balanced persistent grid, R15 structure) -> bf16
  us* at_hi = xkv_hi;
  attn_kernel<<<dim3(512), 256, 0, stream>>>(q_hi, q_lo, kv_hi, kv_lo,
                                             tab_hi, tab_lo, at_hi);
  // 4. out = attn @ to_o^T -> fp32 (plain bf16 MFMA, 64x128 tiles, 512 blocks)
  gemm_out_kernel<<<dim3(8, 64), 256, 0, stream>>>(at_hi, to_hi, out);
}